// Round 1
// baseline (14105.017 us; speedup 1.0000x reference)
//
#include <hip/hip_runtime.h>
#include <math.h>

#define HIDDEN 512
#define INPUT  64
#define NB     64     // distinct batch rows
#define NT     8      // num_trials (identical replicas)
#define WARM   100
#define RESP   400
#define ALPHA  0.1f

// One workgroup per distinct batch row. Thread j owns h[j].
// Per step: sp(h) broadcast via LDS, 512x512 matvec streaming W_rec from L2,
// fused output projection (w_out dot h) via wave shuffle + LDS partials.
__launch_bounds__(512, 1)
__global__ void leaky_rnn_row_kernel(const float* __restrict__ inputs,
                                     const float* __restrict__ W_in,
                                     const float* __restrict__ b_in,
                                     const float* __restrict__ W_rec,
                                     const float* __restrict__ w_out,
                                     const float* __restrict__ b_out,
                                     float* __restrict__ out /*[NB][NT][RESP]*/) {
  const int b = blockIdx.x;
  const int j = threadIdx.x;

  __shared__ float sp[HIDDEN];   // softplus(h) for current step
  __shared__ float xin[INPUT];   // this row's input
  __shared__ float red[8];       // per-wave partials of w_out . h

  if (j < INPUT) xin[j] = inputs[b * INPUT + j];
  __syncthreads();

  // input_contribution[j] (constant across steps)
  float ic = b_in[j];
  const float* wi = W_in + j * INPUT;
#pragma unroll
  for (int i = 0; i < INPUT; ++i) ic = fmaf(xin[i], wi[i], ic);

  const float wout = w_out[j];
  const float bout = b_out[0];
  float h = 0.0f;

  // sp(h0=0) = ln 2
  sp[j] = 0.6931471805599453f;
  __syncthreads();

  const float4* __restrict__ Wr = (const float4*)(W_rec + j * HIDDEN);

  for (int step = 0; step < WARM + RESP; ++step) {
    // rec[j] = sum_k sp[k] * W_rec[j][k]
    float rec = 0.0f;
#pragma unroll 8
    for (int k4 = 0; k4 < HIDDEN / 4; ++k4) {
      float4 w = Wr[k4];
      float4 s = *(const float4*)&sp[4 * k4];  // wave-uniform LDS broadcast
      rec = fmaf(w.x, s.x, rec);
      rec = fmaf(w.y, s.y, rec);
      rec = fmaf(w.z, s.z, rec);
      rec = fmaf(w.w, s.w, rec);
    }
    h = h * (1.0f - ALPHA) + ALPHA * (rec + ic);

    if (step >= WARM) {
      // partial of out = w_out . h
      float v = h * wout;
#pragma unroll
      for (int off = 32; off > 0; off >>= 1) v += __shfl_down(v, off);  // width 64
      if ((j & 63) == 0) red[j >> 6] = v;
    }
    __syncthreads();  // matvec done (sp reusable), red[] visible

    // softplus for next step: stable logaddexp(h, 0)
    sp[j] = fmaxf(h, 0.0f) + log1pf(expf(-fabsf(h)));

    if (step >= WARM && j == 0) {
      float o = bout;
#pragma unroll
      for (int w = 0; w < 8; ++w) o += red[w];
      const float hz = 1.0f / (1.0f + expf(-o));
      const int s = step - WARM;
      float* ob = out + b * (NT * RESP) + s;
#pragma unroll
      for (int t = 0; t < NT; ++t) ob[t * RESP] = hz;  // identical trials
    }
    __syncthreads();  // sp[] ready for next step
  }
}

extern "C" void kernel_launch(void* const* d_in, const int* in_sizes, int n_in,
                              void* d_out, int out_size, void* d_ws, size_t ws_size,
                              hipStream_t stream) {
  const float* inputs = (const float*)d_in[0];
  const float* W_in   = (const float*)d_in[1];
  const float* b_in   = (const float*)d_in[2];
  const float* W_rec  = (const float*)d_in[3];
  const float* w_out  = (const float*)d_in[4];
  const float* b_out  = (const float*)d_in[5];
  float* out = (float*)d_out;

  leaky_rnn_row_kernel<<<dim3(NB), dim3(HIDDEN), 0, stream>>>(
      inputs, W_in, b_in, W_rec, w_out, b_out, out);
}

// Round 2
// 7293.928 us; speedup vs baseline: 1.9338x; 1.9338x over previous
//
#include <hip/hip_runtime.h>
#include <math.h>

#define HIDDEN 512
#define INPUT  64
#define NB     64     // distinct batch rows (8 trials are bit-identical replicas)
#define NT     8
#define WARM   100
#define RESP   400
#define ALPHA  0.1f

typedef _Float16 half8  __attribute__((ext_vector_type(8)));
typedef _Float16 half2v __attribute__((ext_vector_type(2)));

#if defined(__has_builtin)
#  if __has_builtin(__builtin_amdgcn_fdot2)
#    define HAS_FDOT2 1
#  endif
#endif

// One-time fp32 -> f16 conversion of W_rec into workspace.
__global__ void convert_w_kernel(const float* __restrict__ W,
                                 _Float16* __restrict__ Wh, int n) {
  int i = blockIdx.x * blockDim.x + threadIdx.x;
  if (i < n) Wh[i] = (_Float16)W[i];
}

// One wg per distinct batch row; 1024 threads = 2 k-halves x 512 j.
// Thread t: j = t&511, k-half = t>>9. W_rec streamed as f16 from L2,
// sp(h) kept as f16 in LDS, v_dot2_f32_f16 inner product, fp32 state.
__launch_bounds__(1024)
__global__ void leaky_rnn_f16_kernel(const float* __restrict__ inputs,
                                     const float* __restrict__ W_in,
                                     const float* __restrict__ b_in,
                                     const _Float16* __restrict__ Wh,
                                     const float* __restrict__ w_out,
                                     const float* __restrict__ b_out,
                                     float* __restrict__ out /*[NB][NT][RESP]*/) {
  const int b = blockIdx.x;
  const int t = threadIdx.x;
  const int j = t & (HIDDEN - 1);
  const int kh = t >> 9;  // 0 or 1

  __shared__ _Float16 sp_h[HIDDEN];   // softplus(h) as f16
  __shared__ float xin[INPUT];
  __shared__ float redk[HIDDEN];      // k-half-1 partial dots
  __shared__ float wsum[8];           // per-wave w_out.h partials

  if (t < INPUT) xin[t] = inputs[b * INPUT + t];
  __syncthreads();

  float ic = 0.f, wout = 0.f;
  const float bout = b_out[0];
  if (t < HIDDEN) {
    ic = b_in[j];
    const float* wi = W_in + j * INPUT;
#pragma unroll
    for (int i = 0; i < INPUT; ++i) ic = fmaf(xin[i], wi[i], ic);
    wout = w_out[j];
    sp_h[j] = (_Float16)0.6931471805599453f;  // softplus(0)
  }
  float h = 0.f;
  __syncthreads();

  // This thread's W slice: row j, k in [kh*256, kh*256+256), as 32 x half8.
  const half8* __restrict__ Wr =
      (const half8*)(Wh + (size_t)j * HIDDEN + kh * (HIDDEN / 2));
  const half8* sp8 = ((const half8*)sp_h) + kh * (HIDDEN / 16);  // +kh*32

  for (int step = 0; step < WARM + RESP; ++step) {
    float acc = 0.f;
#pragma unroll 8
    for (int i = 0; i < HIDDEN / 16; ++i) {  // 32 iters, 16B W load each
      half8 w = Wr[i];
      half8 s = sp8[i];  // wave-uniform LDS broadcast
#ifdef HAS_FDOT2
      acc = __builtin_amdgcn_fdot2(__builtin_shufflevector(w, w, 0, 1),
                                   __builtin_shufflevector(s, s, 0, 1), acc, false);
      acc = __builtin_amdgcn_fdot2(__builtin_shufflevector(w, w, 2, 3),
                                   __builtin_shufflevector(s, s, 2, 3), acc, false);
      acc = __builtin_amdgcn_fdot2(__builtin_shufflevector(w, w, 4, 5),
                                   __builtin_shufflevector(s, s, 4, 5), acc, false);
      acc = __builtin_amdgcn_fdot2(__builtin_shufflevector(w, w, 6, 7),
                                   __builtin_shufflevector(s, s, 6, 7), acc, false);
#else
#pragma unroll
      for (int l = 0; l < 8; ++l) acc = fmaf((float)w[l], (float)s[l], acc);
#endif
    }

    if (t >= HIDDEN) redk[j] = acc;  // upper k-half publishes partial
    __syncthreads();                 // redk ready; sp_h reads complete

    if (t < HIDDEN) {
      const float rec = acc + redk[j];
      h = h * (1.f - ALPHA) + ALPHA * (rec + ic);
      // stable softplus
      const float sp = fmaxf(h, 0.f) + log1pf(expf(-fabsf(h)));
      sp_h[j] = (_Float16)sp;
      if (step >= WARM) {
        float v = h * wout;
#pragma unroll
        for (int off = 32; off > 0; off >>= 1) v += __shfl_down(v, off);
        if ((t & 63) == 0) wsum[t >> 6] = v;
      }
    }
    __syncthreads();  // new sp_h + wsum visible

    if (step >= WARM && t == 0) {
      float o = bout;
#pragma unroll
      for (int w = 0; w < 8; ++w) o += wsum[w];
      const float hz = 1.f / (1.f + expf(-o));
      const int s = step - WARM;
      float* ob = out + b * (NT * RESP) + s;
#pragma unroll
      for (int tr = 0; tr < NT; ++tr) ob[tr * RESP] = hz;  // identical trials
    }
  }
}

// ---------------- fp32 fallback (round-0 kernel) for tiny ws ----------------
__launch_bounds__(512, 1)
__global__ void leaky_rnn_row_kernel(const float* __restrict__ inputs,
                                     const float* __restrict__ W_in,
                                     const float* __restrict__ b_in,
                                     const float* __restrict__ W_rec,
                                     const float* __restrict__ w_out,
                                     const float* __restrict__ b_out,
                                     float* __restrict__ out) {
  const int b = blockIdx.x;
  const int j = threadIdx.x;
  __shared__ float sp[HIDDEN];
  __shared__ float xin[INPUT];
  __shared__ float red[8];
  if (j < INPUT) xin[j] = inputs[b * INPUT + j];
  __syncthreads();
  float ic = b_in[j];
  const float* wi = W_in + j * INPUT;
#pragma unroll
  for (int i = 0; i < INPUT; ++i) ic = fmaf(xin[i], wi[i], ic);
  const float wout = w_out[j];
  const float bout = b_out[0];
  float h = 0.0f;
  sp[j] = 0.6931471805599453f;
  __syncthreads();
  const float4* __restrict__ Wr = (const float4*)(W_rec + j * HIDDEN);
  for (int step = 0; step < WARM + RESP; ++step) {
    float rec = 0.0f;
#pragma unroll 8
    for (int k4 = 0; k4 < HIDDEN / 4; ++k4) {
      float4 w = Wr[k4];
      float4 s = *(const float4*)&sp[4 * k4];
      rec = fmaf(w.x, s.x, rec);
      rec = fmaf(w.y, s.y, rec);
      rec = fmaf(w.z, s.z, rec);
      rec = fmaf(w.w, s.w, rec);
    }
    h = h * (1.0f - ALPHA) + ALPHA * (rec + ic);
    if (step >= WARM) {
      float v = h * wout;
#pragma unroll
      for (int off = 32; off > 0; off >>= 1) v += __shfl_down(v, off);
      if ((j & 63) == 0) red[j >> 6] = v;
    }
    __syncthreads();
    sp[j] = fmaxf(h, 0.0f) + log1pf(expf(-fabsf(h)));
    if (step >= WARM && j == 0) {
      float o = bout;
#pragma unroll
      for (int w = 0; w < 8; ++w) o += red[w];
      const float hz = 1.0f / (1.0f + expf(-o));
      const int s = step - WARM;
      float* ob = out + b * (NT * RESP) + s;
#pragma unroll
      for (int tr = 0; tr < NT; ++tr) ob[tr * RESP] = hz;
    }
    __syncthreads();
  }
}

extern "C" void kernel_launch(void* const* d_in, const int* in_sizes, int n_in,
                              void* d_out, int out_size, void* d_ws, size_t ws_size,
                              hipStream_t stream) {
  const float* inputs = (const float*)d_in[0];
  const float* W_in   = (const float*)d_in[1];
  const float* b_in   = (const float*)d_in[2];
  const float* W_rec  = (const float*)d_in[3];
  const float* w_out  = (const float*)d_in[4];
  const float* b_out  = (const float*)d_in[5];
  float* out = (float*)d_out;

  const int nW = HIDDEN * HIDDEN;
  if (ws_size >= (size_t)nW * sizeof(_Float16)) {
    _Float16* Wh = (_Float16*)d_ws;
    convert_w_kernel<<<dim3((nW + 255) / 256), dim3(256), 0, stream>>>(W_rec, Wh, nW);
    leaky_rnn_f16_kernel<<<dim3(NB), dim3(2 * HIDDEN), 0, stream>>>(
        inputs, W_in, b_in, Wh, w_out, b_out, out);
  } else {
    leaky_rnn_row_kernel<<<dim3(NB), dim3(HIDDEN), 0, stream>>>(
        inputs, W_in, b_in, W_rec, w_out, b_out, out);
  }
}

// Round 3
// 2250.974 us; speedup vs baseline: 6.2662x; 3.2403x over previous
//
#include <hip/hip_runtime.h>
#include <math.h>

#define HIDDEN 512
#define INPUT  64
#define NB     64     // distinct batch rows (8 trials are bit-identical replicas)
#define NT     8
#define WARM   100
#define RESP   400
#define ALPHA  0.1f

typedef _Float16 half8  __attribute__((ext_vector_type(8)));
typedef _Float16 half2v __attribute__((ext_vector_type(2)));

#if defined(__has_builtin)
#  if __has_builtin(__builtin_amdgcn_fdot2)
#    define HAS_FDOT2 1
#  endif
#endif

// Pack W_rec fp32 [j][k] -> f16 Wpk[k>>3][j][8]: element (j,k) at
// ((k>>3)*HIDDEN + j)*8 + (k&7). A wave reading fixed kblk across consecutive
// j then issues ONE contiguous 1KB load (8 cachelines), vs 64 lines before.
__global__ void convert_w_pack_kernel(const float* __restrict__ W,
                                      _Float16* __restrict__ Wpk) {
  const int t = blockIdx.x * blockDim.x + threadIdx.x;  // HIDDEN*64 threads
  const int kblk = t & 63;   // lanes sweep k-blocks -> coalesced 32B reads
  const int j = t >> 6;
  const float* src = W + (size_t)j * HIDDEN + kblk * 8;
  _Float16* dst = Wpk + ((size_t)kblk * HIDDEN + j) * 8;
#pragma unroll
  for (int l = 0; l < 8; ++l) dst[l] = (_Float16)src[l];
}

// One wg per distinct batch row; 1024 threads = 2 k-halves x 512 j.
// Coalesced packed-W loads, fdot2 inner product, fp32 state, no shuffles
// in the matvec (each thread owns rec_j partial; k-halves merge via LDS).
__launch_bounds__(1024)
__global__ void leaky_rnn_pk_kernel(const float* __restrict__ inputs,
                                    const float* __restrict__ W_in,
                                    const float* __restrict__ b_in,
                                    const _Float16* __restrict__ Wpk,
                                    const float* __restrict__ w_out,
                                    const float* __restrict__ b_out,
                                    float* __restrict__ out /*[NB][NT][RESP]*/) {
  const int b = blockIdx.x;
  const int t = threadIdx.x;
  const int j = t & (HIDDEN - 1);
  const int kh = t >> 9;  // 0 or 1

  __shared__ __align__(16) _Float16 sp_h[HIDDEN];  // softplus(h) as f16
  __shared__ float xin[INPUT];
  __shared__ float redk[HIDDEN];  // upper-k-half partial dots
  __shared__ float wsum[8];       // per-wave w_out.h partials

  if (t < INPUT) xin[t] = inputs[b * INPUT + t];
  __syncthreads();

  float ic = 0.f, wout = 0.f;
  const float bout = b_out[0];
  if (t < HIDDEN) {
    ic = b_in[j];
    const float* wi = W_in + (size_t)j * INPUT;
#pragma unroll
    for (int i = 0; i < INPUT; ++i) ic = fmaf(xin[i], wi[i], ic);
    wout = w_out[j];
    sp_h[j] = (_Float16)0.6931471805599453f;  // softplus(0)
  }
  float h = 0.f;
  __syncthreads();

  // Thread's W chunks: kblk = kh*32 + i, at Wp8[kblk*HIDDEN + j], i = 0..31.
  const half8* __restrict__ Wp8 =
      (const half8*)Wpk + (size_t)(kh * 32) * HIDDEN + j;
  const half8* sp8 = ((const half8*)sp_h) + kh * 32;

  for (int step = 0; step < WARM + RESP; ++step) {
    float acc0 = 0.f, acc1 = 0.f;  // two chains to break fdot2 dep latency
#pragma unroll 16
    for (int i = 0; i < 32; ++i) {
      half8 w = Wp8[(size_t)i * HIDDEN];  // coalesced: lanes 16B apart
      half8 s = sp8[i];                   // wave-uniform LDS broadcast
#ifdef HAS_FDOT2
      acc0 = __builtin_amdgcn_fdot2(__builtin_shufflevector(w, w, 0, 1),
                                    __builtin_shufflevector(s, s, 0, 1), acc0, false);
      acc1 = __builtin_amdgcn_fdot2(__builtin_shufflevector(w, w, 2, 3),
                                    __builtin_shufflevector(s, s, 2, 3), acc1, false);
      acc0 = __builtin_amdgcn_fdot2(__builtin_shufflevector(w, w, 4, 5),
                                    __builtin_shufflevector(s, s, 4, 5), acc0, false);
      acc1 = __builtin_amdgcn_fdot2(__builtin_shufflevector(w, w, 6, 7),
                                    __builtin_shufflevector(s, s, 6, 7), acc1, false);
#else
#pragma unroll
      for (int l = 0; l < 8; ++l)
        ((l & 1) ? acc1 : acc0) = fmaf((float)w[l], (float)s[l], (l & 1) ? acc1 : acc0);
#endif
    }
    const float acc = acc0 + acc1;

    if (t >= HIDDEN) redk[j] = acc;  // upper k-half publishes partial
    __syncthreads();                 // redk ready; all sp_h reads complete

    if (t < HIDDEN) {
      const float rec = acc + redk[j];
      h = h * (1.f - ALPHA) + ALPHA * (rec + ic);
      const float sp = fmaxf(h, 0.f) + log1pf(expf(-fabsf(h)));  // stable softplus
      sp_h[j] = (_Float16)sp;
      if (step >= WARM) {
        float v = h * wout;
#pragma unroll
        for (int off = 32; off > 0; off >>= 1) v += __shfl_down(v, off);
        if ((t & 63) == 0) wsum[t >> 6] = v;
      }
    }
    __syncthreads();  // new sp_h + wsum visible

    if (step >= WARM && t == 0) {
      float o = bout;
#pragma unroll
      for (int w = 0; w < 8; ++w) o += wsum[w];
      const float hz = 1.f / (1.f + expf(-o));
      const int s = step - WARM;
      float* ob = out + (size_t)b * (NT * RESP) + s;
#pragma unroll
      for (int tr = 0; tr < NT; ++tr) ob[tr * RESP] = hz;  // identical trials
    }
  }
}

// ---------------- fp32 fallback (round-0 kernel) for tiny ws ----------------
__launch_bounds__(512, 1)
__global__ void leaky_rnn_row_kernel(const float* __restrict__ inputs,
                                     const float* __restrict__ W_in,
                                     const float* __restrict__ b_in,
                                     const float* __restrict__ W_rec,
                                     const float* __restrict__ w_out,
                                     const float* __restrict__ b_out,
                                     float* __restrict__ out) {
  const int b = blockIdx.x;
  const int j = threadIdx.x;
  __shared__ float sp[HIDDEN];
  __shared__ float xin[INPUT];
  __shared__ float red[8];
  if (j < INPUT) xin[j] = inputs[b * INPUT + j];
  __syncthreads();
  float ic = b_in[j];
  const float* wi = W_in + j * INPUT;
#pragma unroll
  for (int i = 0; i < INPUT; ++i) ic = fmaf(xin[i], wi[i], ic);
  const float wout = w_out[j];
  const float bout = b_out[0];
  float h = 0.0f;
  sp[j] = 0.6931471805599453f;
  __syncthreads();
  const float4* __restrict__ Wr = (const float4*)(W_rec + (size_t)j * HIDDEN);
  for (int step = 0; step < WARM + RESP; ++step) {
    float rec = 0.0f;
#pragma unroll 8
    for (int k4 = 0; k4 < HIDDEN / 4; ++k4) {
      float4 w = Wr[k4];
      float4 s = *(const float4*)&sp[4 * k4];
      rec = fmaf(w.x, s.x, rec);
      rec = fmaf(w.y, s.y, rec);
      rec = fmaf(w.z, s.z, rec);
      rec = fmaf(w.w, s.w, rec);
    }
    h = h * (1.0f - ALPHA) + ALPHA * (rec + ic);
    if (step >= WARM) {
      float v = h * wout;
#pragma unroll
      for (int off = 32; off > 0; off >>= 1) v += __shfl_down(v, off);
      if ((j & 63) == 0) red[j >> 6] = v;
    }
    __syncthreads();
    sp[j] = fmaxf(h, 0.0f) + log1pf(expf(-fabsf(h)));
    if (step >= WARM && j == 0) {
      float o = bout;
#pragma unroll
      for (int w = 0; w < 8; ++w) o += red[w];
      const float hz = 1.0f / (1.0f + expf(-o));
      const int s = step - WARM;
      float* ob = out + (size_t)b * (NT * RESP) + s;
#pragma unroll
      for (int tr = 0; tr < NT; ++tr) ob[tr * RESP] = hz;
    }
    __syncthreads();
  }
}

extern "C" void kernel_launch(void* const* d_in, const int* in_sizes, int n_in,
                              void* d_out, int out_size, void* d_ws, size_t ws_size,
                              hipStream_t stream) {
  const float* inputs = (const float*)d_in[0];
  const float* W_in   = (const float*)d_in[1];
  const float* b_in   = (const float*)d_in[2];
  const float* W_rec  = (const float*)d_in[3];
  const float* w_out  = (const float*)d_in[4];
  const float* b_out  = (const float*)d_in[5];
  float* out = (float*)d_out;

  const int nW = HIDDEN * HIDDEN;
  if (ws_size >= (size_t)nW * sizeof(_Float16)) {
    _Float16* Wpk = (_Float16*)d_ws;
    convert_w_pack_kernel<<<dim3(HIDDEN * 64 / 256), dim3(256), 0, stream>>>(W_rec, Wpk);
    leaky_rnn_pk_kernel<<<dim3(NB), dim3(2 * HIDDEN), 0, stream>>>(
        inputs, W_in, b_in, Wpk, w_out, b_out, out);
  } else {
    leaky_rnn_row_kernel<<<dim3(NB), dim3(HIDDEN), 0, stream>>>(
        inputs, W_in, b_in, W_rec, w_out, b_out, out);
  }
}

// Round 4
// 1045.413 us; speedup vs baseline: 13.4923x; 2.1532x over previous
//
#include <hip/hip_runtime.h>
#include <math.h>

#define HIDDEN 512
#define INPUT  64
#define NB     64     // distinct batch rows (8 trials are bit-identical replicas)
#define NT     8
#define WARM   100
#define RESP   400
#define ALPHA  0.1f

#define NREGC  23     // half8 chunks per thread kept in VGPRs (92 VGPRs)
#define NLDSC  9      // half8 chunks per thread kept in LDS (144 KB)

typedef _Float16 half8 __attribute__((ext_vector_type(8)));

#if defined(__has_builtin)
#  if __has_builtin(__builtin_amdgcn_fdot2)
#    define HAS_FDOT2 1
#  endif
#endif

__device__ __forceinline__ void dot8(half8 w, half8 s, float& a0, float& a1) {
#ifdef HAS_FDOT2
  a0 = __builtin_amdgcn_fdot2(__builtin_shufflevector(w, w, 0, 1),
                              __builtin_shufflevector(s, s, 0, 1), a0, false);
  a1 = __builtin_amdgcn_fdot2(__builtin_shufflevector(w, w, 2, 3),
                              __builtin_shufflevector(s, s, 2, 3), a1, false);
  a0 = __builtin_amdgcn_fdot2(__builtin_shufflevector(w, w, 4, 5),
                              __builtin_shufflevector(s, s, 4, 5), a0, false);
  a1 = __builtin_amdgcn_fdot2(__builtin_shufflevector(w, w, 6, 7),
                              __builtin_shufflevector(s, s, 6, 7), a1, false);
#else
#pragma unroll
  for (int l = 0; l < 8; ++l)
    ((l & 1) ? a1 : a0) = fmaf((float)w[l], (float)s[l], (l & 1) ? a1 : a0);
#endif
}

// Pack W_rec fp32 [j][k] -> f16 Wpk[k>>3][j][8] (coalesced main-kernel loads).
__global__ void convert_w_pack_kernel(const float* __restrict__ W,
                                      _Float16* __restrict__ Wpk) {
  const int t = blockIdx.x * blockDim.x + threadIdx.x;  // HIDDEN*64 threads
  const int kblk = t & 63;
  const int j = t >> 6;
  const float* src = W + (size_t)j * HIDDEN + kblk * 8;
  _Float16* dst = Wpk + ((size_t)kblk * HIDDEN + j) * 8;
#pragma unroll
  for (int l = 0; l < 8; ++l) dst[l] = (_Float16)src[l];
}

// One wg per distinct batch row; 1024 threads = 2 k-halves x 512 j.
// W fully CU-resident: 23/32 chunks in VGPRs, 9/32 in LDS. Zero global
// traffic in the 500-step loop; floor is VALU (fdot2) + LDS read.
__launch_bounds__(1024)
__global__ void leaky_rnn_res_kernel(const float* __restrict__ inputs,
                                     const float* __restrict__ W_in,
                                     const float* __restrict__ b_in,
                                     const _Float16* __restrict__ Wpk,
                                     const float* __restrict__ w_out,
                                     const float* __restrict__ b_out,
                                     float* __restrict__ out /*[NB][NT][RESP]*/) {
  const int b = blockIdx.x;
  const int t = threadIdx.x;
  const int j = t & (HIDDEN - 1);
  const int kh = t >> 9;  // 0 or 1

  __shared__ __align__(16) half8 ldsW[NLDSC][1024];   // 144 KB, chunk-major
  __shared__ __align__(16) _Float16 sp_h[HIDDEN];     // softplus(h) as f16
  __shared__ float xin[INPUT];
  __shared__ float redk[HIDDEN];  // upper-k-half partial dots
  __shared__ float wsum[8];       // per-wave w_out.h partials

  // ---- init: load W into regs + LDS (coalesced: lanes 16B apart) ----
  const half8* __restrict__ Wp8 =
      (const half8*)Wpk + (size_t)(kh * 32) * HIDDEN + j;
  half8 wr[NREGC];
#pragma unroll
  for (int c = 0; c < NREGC; ++c) wr[c] = Wp8[(size_t)c * HIDDEN];
#pragma unroll
  for (int c = 0; c < NLDSC; ++c) ldsW[c][t] = Wp8[(size_t)(NREGC + c) * HIDDEN];

  if (t < INPUT) xin[t] = inputs[b * INPUT + t];
  __syncthreads();  // xin + ldsW visible

  float ic = 0.f, wout = 0.f;
  const float bout = b_out[0];
  if (t < HIDDEN) {
    ic = b_in[j];
    const float* wi = W_in + (size_t)j * INPUT;
#pragma unroll
    for (int i = 0; i < INPUT; ++i) ic = fmaf(xin[i], wi[i], ic);
    wout = w_out[j];
    sp_h[j] = (_Float16)0.6931471805599453f;  // softplus(0)
  }
  float h = 0.f;
  __syncthreads();  // sp_h visible

  const half8* sp8 = ((const half8*)sp_h) + kh * 32;
  float* const ob = out + (size_t)b * (NT * RESP) + (t < NT ? t * RESP : 0);

  for (int step = 0; step < WARM + RESP; ++step) {
    float acc0 = 0.f, acc1 = 0.f;
    // LDS-resident chunks (ds reads issue early, overlap with reg chunks)
#pragma unroll
    for (int c = 0; c < NLDSC; ++c) {
      half8 w = ldsW[c][t];          // 16B-stride lanes: conflict-free
      half8 s = sp8[NREGC + c];      // wave-uniform broadcast
      dot8(w, s, acc0, acc1);
    }
    // register-resident chunks
#pragma unroll
    for (int c = 0; c < NREGC; ++c) {
      half8 s = sp8[c];
      dot8(wr[c], s, acc0, acc1);
    }
    const float acc = acc0 + acc1;

    if (t >= HIDDEN) redk[j] = acc;  // upper k-half publishes partial
    __syncthreads();                 // redk ready; sp_h reads complete

    if (t < HIDDEN) {
      const float rec = acc + redk[j];
      h = h * (1.f - ALPHA) + ALPHA * (rec + ic);
      const float sp = fmaxf(h, 0.f) + log1pf(expf(-fabsf(h)));  // stable softplus
      sp_h[j] = (_Float16)sp;
      if (step >= WARM) {
        float v = h * wout;
#pragma unroll
        for (int off = 32; off > 0; off >>= 1) v += __shfl_down(v, off);
        if ((t & 63) == 0) wsum[t >> 6] = v;
      }
    }
    __syncthreads();  // new sp_h + wsum visible

    if (step >= WARM && t < NT) {
      float o = bout;
#pragma unroll
      for (int w = 0; w < 8; ++w) o += wsum[w];
      const float hz = 1.f / (1.f + expf(-o));
      ob[step - WARM] = hz;  // 8 identical trial copies, one lane each
    }
  }
}

// ---------------- fp32 fallback (round-0 kernel) for tiny ws ----------------
__launch_bounds__(512, 1)
__global__ void leaky_rnn_row_kernel(const float* __restrict__ inputs,
                                     const float* __restrict__ W_in,
                                     const float* __restrict__ b_in,
                                     const float* __restrict__ W_rec,
                                     const float* __restrict__ w_out,
                                     const float* __restrict__ b_out,
                                     float* __restrict__ out) {
  const int b = blockIdx.x;
  const int j = threadIdx.x;
  __shared__ float sp[HIDDEN];
  __shared__ float xin[INPUT];
  __shared__ float red[8];
  if (j < INPUT) xin[j] = inputs[b * INPUT + j];
  __syncthreads();
  float ic = b_in[j];
  const float* wi = W_in + j * INPUT;
#pragma unroll
  for (int i = 0; i < INPUT; ++i) ic = fmaf(xin[i], wi[i], ic);
  const float wout = w_out[j];
  const float bout = b_out[0];
  float h = 0.0f;
  sp[j] = 0.6931471805599453f;
  __syncthreads();
  const float4* __restrict__ Wr = (const float4*)(W_rec + (size_t)j * HIDDEN);
  for (int step = 0; step < WARM + RESP; ++step) {
    float rec = 0.0f;
#pragma unroll 8
    for (int k4 = 0; k4 < HIDDEN / 4; ++k4) {
      float4 w = Wr[k4];
      float4 s = *(const float4*)&sp[4 * k4];
      rec = fmaf(w.x, s.x, rec);
      rec = fmaf(w.y, s.y, rec);
      rec = fmaf(w.z, s.z, rec);
      rec = fmaf(w.w, s.w, rec);
    }
    h = h * (1.0f - ALPHA) + ALPHA * (rec + ic);
    if (step >= WARM) {
      float v = h * wout;
#pragma unroll
      for (int off = 32; off > 0; off >>= 1) v += __shfl_down(v, off);
      if ((j & 63) == 0) red[j >> 6] = v;
    }
    __syncthreads();
    sp[j] = fmaxf(h, 0.0f) + log1pf(expf(-fabsf(h)));
    if (step >= WARM && j == 0) {
      float o = bout;
#pragma unroll
      for (int w = 0; w < 8; ++w) o += red[w];
      const float hz = 1.0f / (1.0f + expf(-o));
      const int s = step - WARM;
      float* obp = out + (size_t)b * (NT * RESP) + s;
#pragma unroll
      for (int tr = 0; tr < NT; ++tr) obp[tr * RESP] = hz;
    }
    __syncthreads();
  }
}

extern "C" void kernel_launch(void* const* d_in, const int* in_sizes, int n_in,
                              void* d_out, int out_size, void* d_ws, size_t ws_size,
                              hipStream_t stream) {
  const float* inputs = (const float*)d_in[0];
  const float* W_in   = (const float*)d_in[1];
  const float* b_in   = (const float*)d_in[2];
  const float* W_rec  = (const float*)d_in[3];
  const float* w_out  = (const float*)d_in[4];
  const float* b_out  = (const float*)d_in[5];
  float* out = (float*)d_out;

  const int nW = HIDDEN * HIDDEN;
  if (ws_size >= (size_t)nW * sizeof(_Float16)) {
    _Float16* Wpk = (_Float16*)d_ws;
    convert_w_pack_kernel<<<dim3(HIDDEN * 64 / 256), dim3(256), 0, stream>>>(W_rec, Wpk);
    leaky_rnn_res_kernel<<<dim3(NB), dim3(2 * HIDDEN), 0, stream>>>(
        inputs, W_in, b_in, Wpk, w_out, b_out, out);
  } else {
    leaky_rnn_row_kernel<<<dim3(NB), dim3(HIDDEN), 0, stream>>>(
        inputs, W_in, b_in, W_rec, w_out, b_out, out);
  }
}